// Round 6
// baseline (106.490 us; speedup 1.0000x reference)
//
#include <hip/hip_runtime.h>
#include <hip/hip_bf16.h>

typedef __bf16 bf16x8 __attribute__((ext_vector_type(8)));
typedef float  f32x4  __attribute__((ext_vector_type(4)));

#define MFMA16(a,b,c) __builtin_amdgcn_mfma_f32_16x16x32_bf16((a),(b),(c),0,0,0)

#define NB 32768
#define CAP 32768   // per-head perm bucket capacity (== B, overflow impossible)

// ---- workspace byte offsets ----
#define WS_CURSORS  64        // 16 int (counts after scatter)
#define WS_PERM     512       // 16 * 32768 int = 2 MB
#define WS_W1P      2097664   // 16384 bf16
#define WS_W2P      2130432   // 65536 bf16
#define WS_HW1P     2261504   // 16*65536 bf16
#define WS_HW2P     4358656   // 16*8192 bf16 (N padded 24->32)
// end: 4620800 bytes

// Coalesced pack: fp32 row-major -> bf16 MFMA B-fragment order, staged via LDS.
// B-frag for (kt,nt): lane holds B[k = kt*32 + (lane>>4)*8 + j][n = nt*16 + (lane&15)], j=0..7.
__global__ __launch_bounds__(256)
void pack_kernel(const float* __restrict__ W1, const float* __restrict__ W2,
                 const float* __restrict__ HW1, const float* __restrict__ HW2,
                 char* __restrict__ ws) {
  __shared__ __bf16 tile[32 * 260];   // pitch 260 bf16 (520 B) breaks pow2 strides
  int b = blockIdx.x, t = threadIdx.x;
  if (b == 0 && t < 32) ((int*)ws)[t] = 0;   // zero control words (incl. cursors)

  const float* src; __bf16* dst; int kt, wstride, hw2 = 0;
  if (b < 2)        { src = W1;  dst = (__bf16*)(ws + WS_W1P); kt = b;      wstride = 4096;  }
  else if (b < 10)  { src = W2;  dst = (__bf16*)(ws + WS_W2P); kt = b - 2;  wstride = 16384; }
  else if (b < 138) { int h = (b - 10) >> 3; kt = (b - 10) & 7;
                      src = HW1 + h*65536; dst = (__bf16*)(ws + WS_HW1P) + h*65536; wstride = 16384; }
  else              { int h = (b - 138) >> 3; kt = (b - 138) & 7;
                      src = HW2 + h*6144;  dst = (__bf16*)(ws + WS_HW2P) + h*8192;  hw2 = 1; }

  int wv = t >> 6, l = t & 63;
  if (!hw2) {
    // stage 32 rows x 256 cols, float4-coalesced
    const float4* s4 = (const float4*)(src + kt*32*256);
#pragma unroll
    for (int p = 0; p < 8; p++) {
      int i = p*256 + t;                 // 0..2047
      int rr = i >> 6, c4 = i & 63;
      float4 v = s4[i];
      __bf16* d = &tile[rr*260 + c4*4];
      d[0] = (__bf16)v.x; d[1] = (__bf16)v.y; d[2] = (__bf16)v.z; d[3] = (__bf16)v.w;
    }
    __syncthreads();
    // wave wv emits the w=wv fragment slice (cols wv*64..wv*64+63): 4 nt frags, 1 KB each
#pragma unroll
    for (int nt = 0; nt < 4; nt++) {
      bf16x8 v;
#pragma unroll
      for (int j = 0; j < 8; j++)
        v[j] = tile[((l>>4)*8 + j)*260 + wv*64 + nt*16 + (l&15)];
      *(bf16x8*)(dst + wv*wstride + (kt*4 + nt)*512 + l*8) = v;
    }
  } else {
    // HW2: 32 rows x 24 cols (pad to 32), pitch 40
    for (int s = t; s < 32*40; s += 256) tile[s] = (__bf16)0.f;
    __syncthreads();
    for (int s = t; s < 768; s += 256) {
      float v = src[kt*768 + s];
      int r = s / 24, c = s - r*24;
      tile[r*40 + c] = (__bf16)v;
    }
    __syncthreads();
    if (wv < 2) {
      int nt = wv;
      bf16x8 v;
#pragma unroll
      for (int j = 0; j < 8; j++) v[j] = tile[((l>>4)*8 + j)*40 + nt*16 + (l&15)];
      *(bf16x8*)(dst + (kt*2 + nt)*512 + l*8) = v;
    }
  }
}

// Block-aggregated counting scatter into fixed-capacity per-head buckets.
__global__ void scatter_kernel(const int* __restrict__ idx, char* __restrict__ ws) {
  __shared__ int lc[16], lbase[16];
  int t = threadIdx.x;
  if (t < 16) lc[t] = 0;
  __syncthreads();
  int b = blockIdx.x * 256 + t;
  int k = idx[b];
  int lp = atomicAdd(&lc[k], 1);
  __syncthreads();
  if (t < 16 && lc[t]) lbase[t] = atomicAdd(&((int*)(ws + WS_CURSORS))[t], lc[t]);
  __syncthreads();
  ((int*)(ws + WS_PERM))[k*CAP + lbase[k] + lp] = b;
}

// GEMM for K=256, N=256: A in LDS (64 x pitch-264 bf16), B pre-packed in global.
// bias + relu, writes result back into the SAME LDS A buffer (barriers inside).
__device__ __forceinline__ void gemm_relu(char* sA, const __bf16* __restrict__ Bp,
                                          const float* __restrict__ bias, int w, int l) {
  int q = l >> 4, l15 = l & 15;
  f32x4 zf = {0.f, 0.f, 0.f, 0.f};
  f32x4 acc[4][4];
#pragma unroll
  for (int mt = 0; mt < 4; mt++)
#pragma unroll
    for (int nt = 0; nt < 4; nt++) acc[mt][nt] = zf;
#pragma unroll
  for (int kt = 0; kt < 8; kt++) {
    bf16x8 af[4], bg[4];
#pragma unroll
    for (int mt = 0; mt < 4; mt++)
      af[mt] = *(const bf16x8*)(sA + (mt*16 + l15)*528 + (kt*32 + q*8)*2);
#pragma unroll
    for (int nt = 0; nt < 4; nt++)
      bg[nt] = *(const bf16x8*)(Bp + w*16384 + (kt*4 + nt)*512 + l*8);
#pragma unroll
    for (int mt = 0; mt < 4; mt++)
#pragma unroll
      for (int nt = 0; nt < 4; nt++)
        acc[mt][nt] = MFMA16(af[mt], bg[nt], acc[mt][nt]);
  }
  __syncthreads();   // all waves done READING sA before we overwrite it
  float bv[4];
#pragma unroll
  for (int nt = 0; nt < 4; nt++) bv[nt] = bias[w*64 + nt*16 + l15];
#pragma unroll
  for (int mt = 0; mt < 4; mt++)
#pragma unroll
    for (int nt = 0; nt < 4; nt++)
#pragma unroll
      for (int r = 0; r < 4; r++) {
        float v = fmaxf(acc[mt][nt][r] + bv[nt], 0.f);
        int row = mt*16 + q*4 + r;
        int col = w*64 + nt*16 + l15;
        *(__bf16*)(sA + row*528 + col*2) = (__bf16)v;
      }
  __syncthreads();
}

__global__ __launch_bounds__(256, 2)
void actor_kernel(const float* __restrict__ obs, const float* __restrict__ noise,
                  const float* __restrict__ b1, const float* __restrict__ b2,
                  const float* __restrict__ Hb1, const float* __restrict__ Hb2,
                  const char* __restrict__ ws, float* __restrict__ out) {
  __shared__ __align__(16) char smem[42240];
  char*  sA    = smem;                    // 64 x 264 bf16, pitch 528B (33792 B)
  float* souts = (float*)(smem + 33792);  // 64 x 32 f32 (8192 B) — separate region, no alias
  int*   rows  = (int*)(smem + 41984);    // 64 ints

  const int* cur  = (const int*)(ws + WS_CURSORS);
  const int* perm = (const int*)(ws + WS_PERM);

  // derive (head, tile) from counts with a 16-iter wave-uniform prefix loop
  int bid = blockIdx.x;
  int accT = 0, head = -1, cnt = 0, tloc = 0;
#pragma unroll
  for (int k = 0; k < 16; k++) {
    int c = cur[k];
    int ntl = (c + 63) >> 6;
    if (head < 0 && bid < accT + ntl) { head = k; tloc = bid - accT; cnt = c; }
    accT += ntl;
  }
  if (head < 0) return;
  int row0  = tloc * 64;
  int nrows = cnt - row0;
  if (nrows > 64) nrows = 64;

  int t = threadIdx.x;
  int w = t >> 6, l = t & 63, q = l >> 4, l15 = l & 15;

  if (t < 64) rows[t] = (t < nrows) ? perm[head*CAP + row0 + t] : -1;

  // G1 B-fragments: load early (independent of rows barrier) to hide latency
  const __bf16* Bp1 = (const __bf16*)(ws + WS_W1P) + w*4096;
  bf16x8 bg1[2][4];
#pragma unroll
  for (int kt = 0; kt < 2; kt++)
#pragma unroll
    for (int nt = 0; nt < 4; nt++)
      bg1[kt][nt] = *(const bf16x8*)(Bp1 + (kt*4 + nt)*512 + l*8);

  __syncthreads();   // rows[] visible

  // ---- GEMM1: h1 = relu(obs @ W1 + b1), K=64, A-frags DIRECT from global obs ----
  {
    f32x4 zf = {0.f, 0.f, 0.f, 0.f};
    f32x4 acc[4][4];
#pragma unroll
    for (int mt = 0; mt < 4; mt++)
#pragma unroll
      for (int nt = 0; nt < 4; nt++) acc[mt][nt] = zf;
    int rm[4];
#pragma unroll
    for (int mt = 0; mt < 4; mt++) {
      int r = rows[mt*16 + l15];
      rm[mt] = (r < 0) ? 0 : r;   // invalid rows read obs[0] (garbage, masked later)
    }
#pragma unroll
    for (int kt = 0; kt < 2; kt++) {
      bf16x8 af[4];
#pragma unroll
      for (int mt = 0; mt < 4; mt++) {
        const float* ap = obs + rm[mt]*64 + kt*32 + q*8;
        f32x4 a0 = *(const f32x4*)ap;
        f32x4 a1 = *(const f32x4*)(ap + 4);
#pragma unroll
        for (int j = 0; j < 4; j++) { af[mt][j] = (__bf16)a0[j]; af[mt][j+4] = (__bf16)a1[j]; }
      }
#pragma unroll
      for (int mt = 0; mt < 4; mt++)
#pragma unroll
        for (int nt = 0; nt < 4; nt++)
          acc[mt][nt] = MFMA16(af[mt], bg1[kt][nt], acc[mt][nt]);
    }
    float bv[4];
#pragma unroll
    for (int nt = 0; nt < 4; nt++) bv[nt] = b1[w*64 + nt*16 + l15];
#pragma unroll
    for (int mt = 0; mt < 4; mt++)
#pragma unroll
      for (int nt = 0; nt < 4; nt++)
#pragma unroll
        for (int r = 0; r < 4; r++) {
          float v = fmaxf(acc[mt][nt][r] + bv[nt], 0.f);
          int row = mt*16 + q*4 + r;
          int col = w*64 + nt*16 + l15;
          *(__bf16*)(sA + row*528 + col*2) = (__bf16)v;
        }
  }
  __syncthreads();

  // ---- GEMM2: h2 = relu(h1 @ W2 + b2) ----
  gemm_relu(sA, (const __bf16*)(ws + WS_W2P), b2, w, l);
  // ---- GEMM3: y = relu(h2 @ HW1[head] + Hb1[head]) ----
  gemm_relu(sA, (const __bf16*)(ws + WS_HW1P) + head*65536, Hb1 + head*256, w, l);

  // ---- GEMM4: out = y @ HW2[head] + Hb2[head], N=24 (padded 32). wave w -> m-tile w ----
  {
    const __bf16* Bp = (const __bf16*)(ws + WS_HW2P) + head*8192;
    f32x4 zf = {0.f, 0.f, 0.f, 0.f};
    f32x4 c4[2]; c4[0] = zf; c4[1] = zf;
#pragma unroll
    for (int kt = 0; kt < 8; kt++) {
      bf16x8 af = *(const bf16x8*)(sA + (w*16 + l15)*528 + (kt*32 + q*8)*2);
#pragma unroll
      for (int nt = 0; nt < 2; nt++) {
        bf16x8 bg = *(const bf16x8*)(Bp + (kt*2 + nt)*512 + l*8);
        c4[nt] = MFMA16(af, bg, c4[nt]);
      }
    }
    // souts is a separate LDS region — safe to write without a barrier
#pragma unroll
    for (int nt = 0; nt < 2; nt++)
#pragma unroll
      for (int r = 0; r < 4; r++) {
        int row = w*16 + q*4 + r;
        int col = nt*16 + l15;
        float v = c4[nt][r];
        if (col < 24) v += Hb2[head*24 + col];
        souts[row*32 + col] = v;
      }
  }
  __syncthreads();

  // ---- postprocess: 4 threads per row, 3 actions each ----
  {
    int row = t >> 2, sub = t & 3;
    int bnum = (row < nrows) ? rows[row] : -1;
    float s = 0.f;
    if (bnum >= 0) {
#pragma unroll
      for (int i = 0; i < 3; i++) {
        int a = sub*3 + i;
        float mean = souts[row*32 + a];
        float lsr  = souts[row*32 + 12 + a];
        float ls   = -10.f + 6.f*(tanhf(lsr) + 1.f);   // LOG_STD_MIN + 0.5*range*(tanh+1)
        float sd   = __expf(ls);
        float nz   = noise[bnum*12 + a];
        float act  = mean + sd*nz;
        float sq   = tanhf(act);
        out[bnum*12 + a] = sq;
        // (act-mean)/std == noise exactly
        s += -0.5f*nz*nz - ls - 0.91893853320467274f - __logf(1.f - sq*sq + 1e-6f);
      }
    }
    s += __shfl_xor(s, 1);
    s += __shfl_xor(s, 2);
    if (bnum >= 0 && sub == 0) out[NB*12 + bnum] = s;
  }
}

extern "C" void kernel_launch(void* const* d_in, const int* in_sizes, int n_in,
                              void* d_out, int out_size, void* d_ws, size_t ws_size,
                              hipStream_t stream) {
  const float* obs   = (const float*)d_in[0];
  const int*   idx   = (const int*)d_in[1];
  const float* noise = (const float*)d_in[2];
  const float* W1    = (const float*)d_in[3];
  const float* b1    = (const float*)d_in[4];
  const float* W2    = (const float*)d_in[5];
  const float* b2    = (const float*)d_in[6];
  const float* HW1   = (const float*)d_in[7];
  const float* Hb1   = (const float*)d_in[8];
  const float* HW2   = (const float*)d_in[9];
  const float* Hb2   = (const float*)d_in[10];
  char* ws = (char*)d_ws;

  pack_kernel<<<266, 256, 0, stream>>>(W1, W2, HW1, HW2, ws);   // also zeros cursors
  scatter_kernel<<<128, 256, 0, stream>>>(idx, ws);
  actor_kernel<<<528, 256, 0, stream>>>(obs, noise, b1, b2, Hb1, Hb2, ws, (float*)d_out);
}

// Round 7
// 104.478 us; speedup vs baseline: 1.0193x; 1.0193x over previous
//
#include <hip/hip_runtime.h>
#include <hip/hip_bf16.h>

typedef __bf16 bf16x8 __attribute__((ext_vector_type(8)));
typedef float  f32x4  __attribute__((ext_vector_type(4)));

#define MFMA16(a,b,c) __builtin_amdgcn_mfma_f32_16x16x32_bf16((a),(b),(c),0,0,0)

#define NB 32768
#define CAP 32768   // per-head perm bucket capacity (== B, overflow impossible)

// ---- workspace byte offsets ----
#define WS_CURSORS  64        // 16 int (zeroed by hipMemsetAsync; counts after prep)
#define WS_PERM     512       // 16 * 32768 int = 2 MB
#define WS_W1P      2097664   // 16384 bf16
#define WS_W2P      2130432   // 65536 bf16
#define WS_HW1P     2261504   // 16*65536 bf16
#define WS_HW2P     4358656   // 16*8192 bf16 (N padded 24->32)
// end: 4620800 bytes

// Fused prep: blocks 0..265 pack weights (fp32 -> bf16 MFMA B-frag order),
// blocks 266..393 scatter row indices into per-head buckets. Disjoint writes.
__global__ __launch_bounds__(256)
void prep_kernel(const float* __restrict__ W1, const float* __restrict__ W2,
                 const float* __restrict__ HW1, const float* __restrict__ HW2,
                 const int* __restrict__ idx, char* __restrict__ ws) {
  int b = blockIdx.x, t = threadIdx.x;

  if (b >= 266) {
    // ---- scatter role (cursors pre-zeroed by memset node) ----
    __shared__ int lc[16], lbase[16];
    if (t < 16) lc[t] = 0;
    __syncthreads();
    int e = (b - 266) * 256 + t;
    int k = idx[e];
    int lp = atomicAdd(&lc[k], 1);
    __syncthreads();
    if (t < 16 && lc[t]) lbase[t] = atomicAdd(&((int*)(ws + WS_CURSORS))[t], lc[t]);
    __syncthreads();
    ((int*)(ws + WS_PERM))[k*CAP + lbase[k] + lp] = e;
    return;
  }

  // ---- pack role ----
  __shared__ __bf16 tile[32 * 260];   // pitch 260 bf16 breaks pow2 strides
  const float* src; __bf16* dst; int kt, wstride, hw2 = 0;
  if (b < 2)        { src = W1;  dst = (__bf16*)(ws + WS_W1P); kt = b;      wstride = 4096;  }
  else if (b < 10)  { src = W2;  dst = (__bf16*)(ws + WS_W2P); kt = b - 2;  wstride = 16384; }
  else if (b < 138) { int h = (b - 10) >> 3; kt = (b - 10) & 7;
                      src = HW1 + h*65536; dst = (__bf16*)(ws + WS_HW1P) + h*65536; wstride = 16384; }
  else              { int h = (b - 138) >> 3; kt = (b - 138) & 7;
                      src = HW2 + h*6144;  dst = (__bf16*)(ws + WS_HW2P) + h*8192;  hw2 = 1; }

  int wv = t >> 6, l = t & 63;
  if (!hw2) {
    const float4* s4 = (const float4*)(src + kt*32*256);
#pragma unroll
    for (int p = 0; p < 8; p++) {
      int i = p*256 + t;
      int rr = i >> 6, c4 = i & 63;
      float4 v = s4[i];
      __bf16* d = &tile[rr*260 + c4*4];
      d[0] = (__bf16)v.x; d[1] = (__bf16)v.y; d[2] = (__bf16)v.z; d[3] = (__bf16)v.w;
    }
    __syncthreads();
#pragma unroll
    for (int nt = 0; nt < 4; nt++) {
      bf16x8 v;
#pragma unroll
      for (int j = 0; j < 8; j++)
        v[j] = tile[((l>>4)*8 + j)*260 + wv*64 + nt*16 + (l&15)];
      *(bf16x8*)(dst + wv*wstride + (kt*4 + nt)*512 + l*8) = v;
    }
  } else {
    for (int s = t; s < 32*40; s += 256) tile[s] = (__bf16)0.f;
    __syncthreads();
    for (int s = t; s < 768; s += 256) {
      float v = src[kt*768 + s];
      int r = s / 24, c = s - r*24;
      tile[r*40 + c] = (__bf16)v;
    }
    __syncthreads();
    if (wv < 2) {
      int nt = wv;
      bf16x8 v;
#pragma unroll
      for (int j = 0; j < 8; j++) v[j] = tile[((l>>4)*8 + j)*40 + nt*16 + (l&15)];
      *(bf16x8*)(dst + (kt*2 + nt)*512 + l*8) = v;
    }
  }
}

// GEMM for K=256, N=256: A in LDS (64 x pitch-264 bf16), B pre-packed in global.
// bias + relu, writes result back into the SAME LDS A buffer (barriers inside).
__device__ __forceinline__ void gemm_relu(char* sA, const __bf16* __restrict__ Bp,
                                          const float* __restrict__ bias, int w, int l) {
  int q = l >> 4, l15 = l & 15;
  f32x4 zf = {0.f, 0.f, 0.f, 0.f};
  f32x4 acc[4][4];
#pragma unroll
  for (int mt = 0; mt < 4; mt++)
#pragma unroll
    for (int nt = 0; nt < 4; nt++) acc[mt][nt] = zf;
#pragma unroll
  for (int kt = 0; kt < 8; kt++) {
    bf16x8 af[4], bg[4];
#pragma unroll
    for (int mt = 0; mt < 4; mt++)
      af[mt] = *(const bf16x8*)(sA + (mt*16 + l15)*528 + (kt*32 + q*8)*2);
#pragma unroll
    for (int nt = 0; nt < 4; nt++)
      bg[nt] = *(const bf16x8*)(Bp + w*16384 + (kt*4 + nt)*512 + l*8);
#pragma unroll
    for (int mt = 0; mt < 4; mt++)
#pragma unroll
      for (int nt = 0; nt < 4; nt++)
        acc[mt][nt] = MFMA16(af[mt], bg[nt], acc[mt][nt]);
  }
  __syncthreads();   // all waves done READING sA before we overwrite it
  float bv[4];
#pragma unroll
  for (int nt = 0; nt < 4; nt++) bv[nt] = bias[w*64 + nt*16 + l15];
#pragma unroll
  for (int mt = 0; mt < 4; mt++)
#pragma unroll
    for (int nt = 0; nt < 4; nt++)
#pragma unroll
      for (int r = 0; r < 4; r++) {
        float v = fmaxf(acc[mt][nt][r] + bv[nt], 0.f);
        int row = mt*16 + q*4 + r;
        int col = w*64 + nt*16 + l15;
        *(__bf16*)(sA + row*528 + col*2) = (__bf16)v;
      }
  __syncthreads();
}

// __launch_bounds__(256,4): cap VGPR at 128 so LDS (42.2 KB) is the occupancy
// limiter -> 3 blocks/CU (was 2 at VGPR>128), 3 waves/SIMD for latency hiding.
__global__ __launch_bounds__(256, 4)
void actor_kernel(const float* __restrict__ obs, const float* __restrict__ noise,
                  const float* __restrict__ b1, const float* __restrict__ b2,
                  const float* __restrict__ Hb1, const float* __restrict__ Hb2,
                  const char* __restrict__ ws, float* __restrict__ out) {
  __shared__ __align__(16) char smem[42240];
  char*  sA    = smem;                    // 64 x 264 bf16, pitch 528B (33792 B)
  float* souts = (float*)(smem + 33792);  // 64 x 32 f32 (8192 B)
  int*   rows  = (int*)(smem + 41984);    // 64 ints

  const int* cur  = (const int*)(ws + WS_CURSORS);
  const int* perm = (const int*)(ws + WS_PERM);

  int bid = blockIdx.x;
  int accT = 0, head = -1, cnt = 0, tloc = 0;
#pragma unroll
  for (int k = 0; k < 16; k++) {
    int c = cur[k];
    int ntl = (c + 63) >> 6;
    if (head < 0 && bid < accT + ntl) { head = k; tloc = bid - accT; cnt = c; }
    accT += ntl;
  }
  if (head < 0) return;
  int row0  = tloc * 64;
  int nrows = cnt - row0;
  if (nrows > 64) nrows = 64;

  int t = threadIdx.x;
  int w = t >> 6, l = t & 63, q = l >> 4, l15 = l & 15;

  if (t < 64) rows[t] = (t < nrows) ? perm[head*CAP + row0 + t] : -1;
  __syncthreads();

  // ---- GEMM1: h1 = relu(obs @ W1 + b1), K=64, A-frags direct from global obs ----
  {
    const __bf16* Bp1 = (const __bf16*)(ws + WS_W1P) + w*4096;
    f32x4 zf = {0.f, 0.f, 0.f, 0.f};
    f32x4 acc[4][4];
#pragma unroll
    for (int mt = 0; mt < 4; mt++)
#pragma unroll
      for (int nt = 0; nt < 4; nt++) acc[mt][nt] = zf;
    int rm[4];
#pragma unroll
    for (int mt = 0; mt < 4; mt++) {
      int r = rows[mt*16 + l15];
      rm[mt] = (r < 0) ? 0 : r;
    }
#pragma unroll
    for (int kt = 0; kt < 2; kt++) {
      bf16x8 af[4];
#pragma unroll
      for (int mt = 0; mt < 4; mt++) {
        const float* ap = obs + rm[mt]*64 + kt*32 + q*8;
        f32x4 a0 = *(const f32x4*)ap;
        f32x4 a1 = *(const f32x4*)(ap + 4);
#pragma unroll
        for (int j = 0; j < 4; j++) { af[mt][j] = (__bf16)a0[j]; af[mt][j+4] = (__bf16)a1[j]; }
      }
      bf16x8 bg[4];
#pragma unroll
      for (int nt = 0; nt < 4; nt++)
        bg[nt] = *(const bf16x8*)(Bp1 + (kt*4 + nt)*512 + l*8);
#pragma unroll
      for (int mt = 0; mt < 4; mt++)
#pragma unroll
        for (int nt = 0; nt < 4; nt++)
          acc[mt][nt] = MFMA16(af[mt], bg[nt], acc[mt][nt]);
    }
    float bv[4];
#pragma unroll
    for (int nt = 0; nt < 4; nt++) bv[nt] = b1[w*64 + nt*16 + l15];
#pragma unroll
    for (int mt = 0; mt < 4; mt++)
#pragma unroll
      for (int nt = 0; nt < 4; nt++)
#pragma unroll
        for (int r = 0; r < 4; r++) {
          float v = fmaxf(acc[mt][nt][r] + bv[nt], 0.f);
          int row = mt*16 + q*4 + r;
          int col = w*64 + nt*16 + l15;
          *(__bf16*)(sA + row*528 + col*2) = (__bf16)v;
        }
  }
  __syncthreads();

  // ---- GEMM2: h2 = relu(h1 @ W2 + b2) ----
  gemm_relu(sA, (const __bf16*)(ws + WS_W2P), b2, w, l);
  // ---- GEMM3: y = relu(h2 @ HW1[head] + Hb1[head]) ----
  gemm_relu(sA, (const __bf16*)(ws + WS_HW1P) + head*65536, Hb1 + head*256, w, l);

  // ---- GEMM4: out = y @ HW2[head] + Hb2[head], N=24 (padded 32). wave w -> m-tile w ----
  {
    const __bf16* Bp = (const __bf16*)(ws + WS_HW2P) + head*8192;
    f32x4 zf = {0.f, 0.f, 0.f, 0.f};
    f32x4 c4[2]; c4[0] = zf; c4[1] = zf;
#pragma unroll
    for (int kt = 0; kt < 8; kt++) {
      bf16x8 af = *(const bf16x8*)(sA + (w*16 + l15)*528 + (kt*32 + q*8)*2);
#pragma unroll
      for (int nt = 0; nt < 2; nt++) {
        bf16x8 bg = *(const bf16x8*)(Bp + (kt*2 + nt)*512 + l*8);
        c4[nt] = MFMA16(af, bg, c4[nt]);
      }
    }
#pragma unroll
    for (int nt = 0; nt < 2; nt++)
#pragma unroll
      for (int r = 0; r < 4; r++) {
        int row = w*16 + q*4 + r;
        int col = nt*16 + l15;
        float v = c4[nt][r];
        if (col < 24) v += Hb2[head*24 + col];
        souts[row*32 + col] = v;
      }
  }
  __syncthreads();

  // ---- postprocess: 4 threads per row, 3 actions each ----
  {
    int row = t >> 2, sub = t & 3;
    int bnum = (row < nrows) ? rows[row] : -1;
    float s = 0.f;
    if (bnum >= 0) {
#pragma unroll
      for (int i = 0; i < 3; i++) {
        int a = sub*3 + i;
        float mean = souts[row*32 + a];
        float lsr  = souts[row*32 + 12 + a];
        float ls   = -10.f + 6.f*(tanhf(lsr) + 1.f);
        float sd   = __expf(ls);
        float nz   = noise[bnum*12 + a];
        float act  = mean + sd*nz;
        float sq   = tanhf(act);
        out[bnum*12 + a] = sq;
        s += -0.5f*nz*nz - ls - 0.91893853320467274f - __logf(1.f - sq*sq + 1e-6f);
      }
    }
    s += __shfl_xor(s, 1);
    s += __shfl_xor(s, 2);
    if (bnum >= 0 && sub == 0) out[NB*12 + bnum] = s;
  }
}

extern "C" void kernel_launch(void* const* d_in, const int* in_sizes, int n_in,
                              void* d_out, int out_size, void* d_ws, size_t ws_size,
                              hipStream_t stream) {
  const float* obs   = (const float*)d_in[0];
  const int*   idx   = (const int*)d_in[1];
  const float* noise = (const float*)d_in[2];
  const float* W1    = (const float*)d_in[3];
  const float* b1    = (const float*)d_in[4];
  const float* W2    = (const float*)d_in[5];
  const float* b2    = (const float*)d_in[6];
  const float* HW1   = (const float*)d_in[7];
  const float* Hb1   = (const float*)d_in[8];
  const float* HW2   = (const float*)d_in[9];
  const float* Hb2   = (const float*)d_in[10];
  char* ws = (char*)d_ws;

  hipMemsetAsync(ws + WS_CURSORS, 0, 64, stream);   // zero the 16 scatter cursors
  prep_kernel<<<394, 256, 0, stream>>>(W1, W2, HW1, HW2, idx, ws);
  actor_kernel<<<528, 256, 0, stream>>>(obs, noise, b1, b2, Hb1, Hb2, ws, (float*)d_out);
}